// Round 9
// baseline (39.105 us; speedup 1.0000x reference)
//
#include <hip/hip_runtime.h>
#include <math.h>

namespace {

constexpr int kT = 16384;     // time steps per row
constexpr int kC = 64;        // channels
constexpr int kL = 128;       // EMA kernel length
constexpr int kThreads = 256;
constexpr int kChunk = 8;                    // elements per thread per tile
constexpr int kSub = kThreads * kChunk;      // 2048 per tile
constexpr int kSpan = 8192;                  // per-block span (half row)
constexpr int kIters = kSpan / kSub;         // 4 tiles per block
constexpr int kHC = kL / kChunk;             // 16 carry chunks
constexpr float kEps = 1e-6f;

// Native clang vector (NOT HIP_vector_type) -- required by the NT builtin.
typedef float floatx4 __attribute__((ext_vector_type(4)));

// Single-instruction HW transcendentals (v_exp_f32 / v_log_f32, ~1 ULP).
__device__ __forceinline__ float fexp2(float v) { return __builtin_amdgcn_exp2f(v); }
__device__ __forceinline__ float flog2(float v) { return __builtin_amdgcn_logf(v); }

constexpr float kLog2e  = 1.4426950408889634f;
constexpr float kRlog2e = 0.6931471805599453f;

__device__ __forceinline__ float fsigmoid(float z) {
  return 1.f / (1.f + fexp2(-z * kLog2e));
}
__device__ __forceinline__ float fsoftplus(float v) {  // args here are O(1)
  return flog2(1.f + fexp2(v * kLog2e)) * kRlog2e;
}

__device__ __forceinline__ float4 ld4g(const float* p) { return *(const float4*)p; }

// Nontemporal store: output is write-once, never read -> don't allocate in
// L2/MALL, so the input stays L3-resident across replays (FETCH -> ~0).
__device__ __forceinline__ void st4nt(float* p, float a, float b, float c, float d) {
  floatx4 v = {a, b, c, d};
  __builtin_nontemporal_store(v, (floatx4*)p);
}

// 8-term geometric Horner over |a|,|b|
__device__ __forceinline__ float horner8(float4 a, float4 b, float r) {
  float B = fabsf(a.x);
  B = fmaf(B, r, fabsf(a.y)); B = fmaf(B, r, fabsf(a.z));
  B = fmaf(B, r, fabsf(a.w)); B = fmaf(B, r, fabsf(b.x));
  B = fmaf(B, r, fabsf(b.y)); B = fmaf(B, r, fabsf(b.z));
  B = fmaf(B, r, fabsf(b.w));
  return B;
}

__global__ __launch_bounds__(kThreads, 8) void pcen_kernel(
    const float* __restrict__ x,
    const float* __restrict__ log_alpha,
    const float* __restrict__ log_delta,
    const float* __restrict__ log_root,
    const float* __restrict__ log_s,
    float* __restrict__ out)
{
  __shared__ float bs[2][kHC + kThreads];   // double-buffered chunk sums

  const int tid = threadIdx.x;
  const int row = blockIdx.x >> 1;          // b*C + c  (2 blocks per row)
  const int tb0 = (blockIdx.x & 1) * kSpan; // span start within row
  const int c   = row & (kC - 1);

  const float* __restrict__ xr   = x + (size_t)row * kT;
  float* __restrict__       outr = out + (size_t)row * kT;

  // ---- tile-0 loads issued first (latency overlaps param math) ----
  const int base0 = tb0 + kChunk * tid;
  float4 v0 = ld4g(xr + base0);
  float4 v1 = ld4g(xr + base0 + 4);
  float4 o0 = make_float4(0.f, 0.f, 0.f, 0.f), o1 = o0;
  if (base0 >= kL) {                        // x[t-128] (L1/L2 hit)
    o0 = ld4g(xr + base0 - kL);
    o1 = ld4g(xr + base0 - kL + 4);
  }
  float4 h0 = make_float4(0.f, 0.f, 0.f, 0.f), h1 = h0;
  if (tid < kHC && tb0) {                   // 128-elem halo, once per block
    h0 = ld4g(xr + tb0 - kL + kChunk * tid);
    h1 = ld4g(xr + tb0 - kL + kChunk * tid + 4);
  }

  // ---- per-channel parameters, once per block ----
  const float s    = fsigmoid(log_s[c]);
  const float r    = 1.f - s;
  const float r2   = r * r;
  const float r4   = r2 * r2;
  const float r8   = r4 * r4;
  const float r16  = r8 * r8;
  const float r32  = r16 * r16;
  const float r64  = r32 * r32;
  const float r128 = r64 * r64;
  const float kn   = s / ((1.f - r128) + 1e-8f);   // s / (impulse sum + 1e-8)
  const float alpha = fsigmoid(log_alpha[c]);
  const float delta = fsoftplus(log_delta[c]) + 1e-6f;
  const float root  = fsoftplus(log_root[c]) + 0.1f;
  const float dr    = fexp2(root * flog2(delta));  // delta^root

  // ---- tile-0 carry slots from halo (zeros when tb0 == 0) ----
  if (tid < kHC) bs[0][tid] = horner8(h0, h1, r);

  // ---- 4-tile pipelined loop: prefetch i+1, compute/store i ----
  #pragma unroll
  for (int i = 0; i < kIters; ++i) {
    const int b  = i & 1;
    const int cb = tb0 + i * kSub + kChunk * tid;

    // prefetch next tile (registers; consumed after the swap)
    float4 nv0, nv1, no0, no1;
    if (i < kIters - 1) {
      nv0 = ld4g(xr + cb + kSub);
      nv1 = ld4g(xr + cb + kSub + 4);
      no0 = ld4g(xr + cb + kSub - kL);      // always >= 0 here
      no1 = ld4g(xr + cb + kSub - kL + 4);
    }

    // chunk sum for this tile
    bs[b][kHC + tid] = horner8(v0, v1, r);
    if (i > 0 && tid < kHC)                 // carry = prev tile's last 16 sums
      bs[b][tid] = bs[1 - b][kThreads + tid];
    __syncthreads();

    // S[cb-1]: 16-term Horner over carry window, two chains for latency
    float Sa = bs[b][tid + 0];
    float Sb = bs[b][tid + 1];
    #pragma unroll
    for (int m = 2; m < kHC; m += 2) {
      Sa = fmaf(Sa, r16, bs[b][tid + m]);
      Sb = fmaf(Sb, r16, bs[b][tid + m + 1]);
    }
    float S = fmaf(Sa, r8, Sb);

    // recurrence + PCEN pointwise
    const float xv[kChunk] = {fabsf(v0.x), fabsf(v0.y), fabsf(v0.z), fabsf(v0.w),
                              fabsf(v1.x), fabsf(v1.y), fabsf(v1.z), fabsf(v1.w)};
    const float ol[kChunk] = {fabsf(o0.x), fabsf(o0.y), fabsf(o0.z), fabsf(o0.w),
                              fabsf(o1.x), fabsf(o1.y), fabsf(o1.z), fabsf(o1.w)};
    float res[kChunk];
    #pragma unroll
    for (int j = 0; j < kChunk; ++j) {
      S = fmaf(S, r, xv[j]);
      S = fmaf(-r128, ol[j], S);
      const float M      = kn * S;
      const float ginv   = fexp2(-alpha * flog2(kEps + M));  // (eps+M)^-alpha
      const float normed = xv[j] * ginv;
      res[j] = fexp2(root * flog2(normed + delta)) - dr;
    }

    st4nt(outr + cb,     res[0], res[1], res[2], res[3]);
    st4nt(outr + cb + 4, res[4], res[5], res[6], res[7]);

    if (i < kIters - 1) { v0 = nv0; v1 = nv1; o0 = no0; o1 = no1; }
  }
}

} // namespace

extern "C" void kernel_launch(void* const* d_in, const int* in_sizes, int n_in,
                              void* d_out, int out_size, void* d_ws, size_t ws_size,
                              hipStream_t stream) {
  const float* x  = (const float*)d_in[0];
  const float* la = (const float*)d_in[1];
  const float* ld = (const float*)d_in[2];
  const float* lr = (const float*)d_in[3];
  const float* ls = (const float*)d_in[4];
  float* out = (float*)d_out;

  constexpr int rows = 16 * 64;              // B*C
  constexpr int blocksPerRow = kT / kSpan;   // 2
  constexpr int grid = rows * blocksPerRow;  // 2048 blocks = 8/CU, fully resident

  hipLaunchKernelGGL(pcen_kernel, dim3(grid), dim3(kThreads), 0, stream,
                     x, la, ld, lr, ls, out);
}

// Round 10
// 25.577 us; speedup vs baseline: 1.5289x; 1.5289x over previous
//
#include <hip/hip_runtime.h>
#include <math.h>

namespace {

constexpr int kT = 16384;     // time steps per row
constexpr int kC = 64;        // channels
constexpr int kL = 128;       // EMA kernel length
constexpr int kThreads = 256;
constexpr int kChunk = 8;                    // elements per thread per tile
constexpr int kSub = kThreads * kChunk;      // 2048 per tile
constexpr int kSpan = 8192;                  // per-block span (half row)
constexpr int kIters = kSpan / kSub;         // 4 tiles per block
constexpr int kHC = kL / kChunk;             // 16 carry chunks
constexpr float kEps = 1e-6f;

// Single-instruction HW transcendentals (v_exp_f32 / v_log_f32, ~1 ULP).
__device__ __forceinline__ float fexp2(float v) { return __builtin_amdgcn_exp2f(v); }
__device__ __forceinline__ float flog2(float v) { return __builtin_amdgcn_logf(v); }

constexpr float kLog2e  = 1.4426950408889634f;
constexpr float kRlog2e = 0.6931471805599453f;

__device__ __forceinline__ float fsigmoid(float z) {
  return 1.f / (1.f + fexp2(-z * kLog2e));
}
__device__ __forceinline__ float fsoftplus(float v) {  // args here are O(1)
  return flog2(1.f + fexp2(v * kLog2e)) * kRlog2e;
}

__device__ __forceinline__ float4 ld4g(const float* p) { return *(const float4*)p; }

// 8-term geometric Horner over |a|,|b|
__device__ __forceinline__ float horner8(float4 a, float4 b, float r) {
  float B = fabsf(a.x);
  B = fmaf(B, r, fabsf(a.y)); B = fmaf(B, r, fabsf(a.z));
  B = fmaf(B, r, fabsf(a.w)); B = fmaf(B, r, fabsf(b.x));
  B = fmaf(B, r, fabsf(b.y)); B = fmaf(B, r, fabsf(b.z));
  B = fmaf(B, r, fabsf(b.w));
  return B;
}

__global__ __launch_bounds__(kThreads, 8) void pcen_kernel(
    const float* __restrict__ x,
    const float* __restrict__ log_alpha,
    const float* __restrict__ log_delta,
    const float* __restrict__ log_root,
    const float* __restrict__ log_s,
    float* __restrict__ out)
{
  __shared__ float bs[2][kHC + kThreads];   // double-buffered chunk sums

  const int tid = threadIdx.x;
  const int row = blockIdx.x >> 1;          // b*C + c  (2 blocks per row)
  const int tb0 = (blockIdx.x & 1) * kSpan; // span start within row
  const int c   = row & (kC - 1);

  const float* __restrict__ xr   = x + (size_t)row * kT;
  float* __restrict__       outr = out + (size_t)row * kT;

  // ---- tile-0 loads issued first (latency overlaps param math) ----
  const int base0 = tb0 + kChunk * tid;
  float4 v0 = ld4g(xr + base0);
  float4 v1 = ld4g(xr + base0 + 4);
  float4 o0 = make_float4(0.f, 0.f, 0.f, 0.f), o1 = o0;
  if (base0 >= kL) {                        // x[t-128] (L1/L2 hit)
    o0 = ld4g(xr + base0 - kL);
    o1 = ld4g(xr + base0 - kL + 4);
  }
  float4 h0 = make_float4(0.f, 0.f, 0.f, 0.f), h1 = h0;
  if (tid < kHC && tb0) {                   // 128-elem halo, once per block
    h0 = ld4g(xr + tb0 - kL + kChunk * tid);
    h1 = ld4g(xr + tb0 - kL + kChunk * tid + 4);
  }

  // ---- per-channel parameters, once per block ----
  const float s    = fsigmoid(log_s[c]);
  const float r    = 1.f - s;
  const float r2   = r * r;
  const float r4   = r2 * r2;
  const float r8   = r4 * r4;
  const float r16  = r8 * r8;
  const float r32  = r16 * r16;
  const float r64  = r32 * r32;
  const float r128 = r64 * r64;
  const float kn   = s / ((1.f - r128) + 1e-8f);   // s / (impulse sum + 1e-8)
  const float alpha = fsigmoid(log_alpha[c]);
  const float delta = fsoftplus(log_delta[c]) + 1e-6f;
  const float root  = fsoftplus(log_root[c]) + 0.1f;
  const float dr    = fexp2(root * flog2(delta));  // delta^root

  // ---- tile-0 carry slots from halo (zeros when tb0 == 0) ----
  if (tid < kHC) bs[0][tid] = horner8(h0, h1, r);

  // ---- 4-tile pipelined loop: prefetch i+1, compute/store i ----
  #pragma unroll
  for (int i = 0; i < kIters; ++i) {
    const int b  = i & 1;
    const int cb = tb0 + i * kSub + kChunk * tid;

    // prefetch next tile (registers; consumed after the swap)
    float4 nv0, nv1, no0, no1;
    if (i < kIters - 1) {
      nv0 = ld4g(xr + cb + kSub);
      nv1 = ld4g(xr + cb + kSub + 4);
      no0 = ld4g(xr + cb + kSub - kL);      // always >= 0 here
      no1 = ld4g(xr + cb + kSub - kL + 4);
    }

    // chunk sum for this tile
    bs[b][kHC + tid] = horner8(v0, v1, r);
    if (i > 0 && tid < kHC)                 // carry = prev tile's last 16 sums
      bs[b][tid] = bs[1 - b][kThreads + tid];
    __syncthreads();

    // S[cb-1]: 16-term Horner over carry window, two chains for latency
    float Sa = bs[b][tid + 0];
    float Sb = bs[b][tid + 1];
    #pragma unroll
    for (int m = 2; m < kHC; m += 2) {
      Sa = fmaf(Sa, r16, bs[b][tid + m]);
      Sb = fmaf(Sb, r16, bs[b][tid + m + 1]);
    }
    float S = fmaf(Sa, r8, Sb);

    // recurrence + PCEN pointwise
    const float xv[kChunk] = {fabsf(v0.x), fabsf(v0.y), fabsf(v0.z), fabsf(v0.w),
                              fabsf(v1.x), fabsf(v1.y), fabsf(v1.z), fabsf(v1.w)};
    const float ol[kChunk] = {fabsf(o0.x), fabsf(o0.y), fabsf(o0.z), fabsf(o0.w),
                              fabsf(o1.x), fabsf(o1.y), fabsf(o1.z), fabsf(o1.w)};
    float res[kChunk];
    #pragma unroll
    for (int j = 0; j < kChunk; ++j) {
      S = fmaf(S, r, xv[j]);
      S = fmaf(-r128, ol[j], S);
      const float M      = kn * S;
      const float ginv   = fexp2(-alpha * flog2(kEps + M));  // (eps+M)^-alpha
      const float normed = xv[j] * ginv;
      res[j] = fexp2(root * flog2(normed + delta)) - dr;
    }

    *(float4*)(outr + cb)     = make_float4(res[0], res[1], res[2], res[3]);
    *(float4*)(outr + cb + 4) = make_float4(res[4], res[5], res[6], res[7]);

    if (i < kIters - 1) { v0 = nv0; v1 = nv1; o0 = no0; o1 = no1; }
  }
}

} // namespace

extern "C" void kernel_launch(void* const* d_in, const int* in_sizes, int n_in,
                              void* d_out, int out_size, void* d_ws, size_t ws_size,
                              hipStream_t stream) {
  const float* x  = (const float*)d_in[0];
  const float* la = (const float*)d_in[1];
  const float* ld = (const float*)d_in[2];
  const float* lr = (const float*)d_in[3];
  const float* ls = (const float*)d_in[4];
  float* out = (float*)d_out;

  constexpr int rows = 16 * 64;              // B*C
  constexpr int blocksPerRow = kT / kSpan;   // 2
  constexpr int grid = rows * blocksPerRow;  // 2048 blocks = 8/CU, fully resident

  hipLaunchKernelGGL(pcen_kernel, dim3(grid), dim3(kThreads), 0, stream,
                     x, la, ld, lr, ls, out);
}